// Round 1
// baseline (1616.786 us; speedup 1.0000x reference)
//
#include <hip/hip_runtime.h>
#include <hip/hip_bf16.h>

#define BB 16
#define LL 4096
#define DD 64

typedef __attribute__((ext_vector_type(8))) short bf16x8;
typedef __attribute__((ext_vector_type(4))) float f32x4;

// sP row stride (shorts). 72 = 64 + 8 pad: fragment ds_read_b128 from row*72
// lands (row+quad)*4 bank starts -> conflict-free (carried from verified kernel).
#define PST 72

__device__ __forceinline__ short f2bf(float f) {
    unsigned u = __builtin_bit_cast(unsigned, f);
    u += 0x7FFFu + ((u >> 16) & 1u);   // RNE; inputs are finite
    return (short)(u >> 16);
}

// ================= prologue: K f32->bf16 copy, V f32->bf16 transpose =================
// Kb: [B][L][D] bf16 (natural). Vt: [B][D][L] bf16 (transposed, so PV B-fragments
// are contiguous 16B loads along the key axis).
__global__ void __launch_bounds__(256)
prep_kv(const float* __restrict__ Km, const float* __restrict__ Vm,
        short* __restrict__ Kb, short* __restrict__ Vt)
{
    __shared__ short sVt[64 * PST];
    const int tid = threadIdx.x;
    const int kb = blockIdx.x, b = blockIdx.y;
    const size_t tbase = ((size_t)(b * LL + (kb << 6))) << 6;   // tile base (elements)

    // K: straight convert, coalesced both sides
    const float* kp = Km + tbase;
    short* ko = Kb + tbase;
    #pragma unroll
    for (int i = 0; i < 4; ++i) {
        const int e = (i * 256 + tid) << 2;
        float4 x = *(const float4*)(kp + e);
        short4 s; s.x = f2bf(x.x); s.y = f2bf(x.y); s.z = f2bf(x.z); s.w = f2bf(x.w);
        *(short4*)(ko + e) = s;
    }

    // V: coalesced f32 read -> transposed bf16 LDS tile -> coalesced bf16 write
    const float* vp = Vm + tbase;
    #pragma unroll
    for (int i = 0; i < 4; ++i) {
        const int task = i * 256 + tid;
        const int l = task >> 4, d4 = task & 15;
        float4 x = *(const float4*)(vp + (l << 6) + (d4 << 2));
        sVt[(d4 * 4 + 0) * PST + l] = f2bf(x.x);
        sVt[(d4 * 4 + 1) * PST + l] = f2bf(x.y);
        sVt[(d4 * 4 + 2) * PST + l] = f2bf(x.z);
        sVt[(d4 * 4 + 3) * PST + l] = f2bf(x.w);
    }
    __syncthreads();
    #pragma unroll
    for (int i = 0; i < 2; ++i) {
        const int task = i * 256 + tid;
        const int d = task >> 3, c = task & 7;
        bf16x8 v = *(bf16x8*)&sVt[d * PST + (c << 3)];
        *(bf16x8*)(Vt + (((size_t)(b * 64 + d)) << 12) + (kb << 6) + (c << 3)) = v;
    }
}

// ================= main fused attention =================
// No LDS staging of K/V: fragments load directly from bf16 global (L1/L2/L3-hot,
// K+V per batch = 1 MB bf16). Zero __syncthreads in both K loops; sP is
// wave-private so only lgkmcnt ordering (compiler-inserted) is needed.
__global__ void __launch_bounds__(256)
attn_fused(const float* __restrict__ Q, const short* __restrict__ Kb,
           const short* __restrict__ Vt, const unsigned char* __restrict__ Mask,
           float* __restrict__ Out, float* __restrict__ Attn)
{
    __shared__ short sP[4][16 * PST];       // per-wave P tile [qrow][key] bf16
    __shared__ unsigned char sPad[64];
    __shared__ int sAny;

    const int tid  = threadIdx.x;
    const int wave = tid >> 6, lane = tid & 63;
    const int l15  = lane & 15, quad = lane >> 4;
    const int b = blockIdx.y;
    const int qt = (int)gridDim.x - 1 - (int)blockIdx.x;  // heavy tiles dispatch first
    const int q0 = qt << 6;

    if (tid < 64) sPad[tid] = (Mask[b * LL + q0 + tid] != 0) ? 1 : 0;
    __syncthreads();
    if (wave == 0) {
        unsigned long long bm = __ballot(sPad[lane] != 0);
        if (lane == 0) sAny = (bm != 0ull) ? 1 : 0;
    }
    __syncthreads();
    const int kbCount = sAny ? (LL >> 6) : (qt + 1);

    // ---- zero-fill attn cols >= kbCount*64 for this block's 64 rows ----
    {
        const float4 z = make_float4(0.f, 0.f, 0.f, 0.f);
        const int cstart = kbCount << 6;
        for (int r = 0; r < 16; ++r) {
            const int rg = q0 + (wave << 4) + r;
            float* rp = Attn + ((size_t)(b * LL + rg) << 12);
            for (int c = cstart + (lane << 2); c < LL; c += 256)
                *(float4*)(rp + c) = z;
        }
    }

    // ---- Q fragments (A layout: m=lane&15, k=quad*8+j, two K-steps) ----
    bf16x8 aq[2];
    {
        const float* qp = Q + (((size_t)(b * LL + q0 + (wave << 4) + l15)) << 6) + (quad << 3);
        #pragma unroll
        for (int ks = 0; ks < 2; ++ks) {
            float4 f0 = *(const float4*)(qp + ks * 32);
            float4 f1 = *(const float4*)(qp + ks * 32 + 4);
            bf16x8 a;
            a[0] = f2bf(f0.x); a[1] = f2bf(f0.y); a[2] = f2bf(f0.z); a[3] = f2bf(f0.w);
            a[4] = f2bf(f1.x); a[5] = f2bf(f1.y); a[6] = f2bf(f1.z); a[7] = f2bf(f1.w);
            aq[ks] = a;
        }
    }

    // exp(s/(T+EPS)) == exp2(s * log2(e)/(T+EPS))
    const float SCL2 = 1.4426950408889634f / 8.000001f;

    // C/D layout: row = quad*4 + reg, col = lane&15 (m89/m91 verified)
    int rowg[4]; int padr[4]; float* attnRow[4];
    #pragma unroll
    for (int r = 0; r < 4; ++r) {
        const int rl = (wave << 4) + quad * 4 + r;
        rowg[r] = q0 + rl;
        padr[r] = sPad[rl];
        attnRow[r] = Attn + ((size_t)(b * LL + rowg[r]) << 12);
    }

    const short* kb_base = Kb + (((size_t)b * LL) << 6) + (quad << 3);
    const short* vt_base = Vt + (((size_t)b * 64) << 12) + (quad << 3);

    // ================= pass 1: softmax denominators =================
    float lsum[4] = {0.f, 0.f, 0.f, 0.f};
    for (int kb = 0; kb < kbCount; ++kb) {
        const short* kp = kb_base + (kb << 12);
        bf16x8 bk[4][2];
        #pragma unroll
        for (int sub = 0; sub < 4; ++sub) {
            bk[sub][0] = *(const bf16x8*)(kp + ((sub * 16 + l15) << 6));
            bk[sub][1] = *(const bf16x8*)(kp + ((sub * 16 + l15) << 6) + 32);
        }
        #pragma unroll
        for (int sub = 0; sub < 4; ++sub) {
            f32x4 acc = {0.f, 0.f, 0.f, 0.f};
            acc = __builtin_amdgcn_mfma_f32_16x16x32_bf16(aq[0], bk[sub][0], acc, 0, 0, 0);
            acc = __builtin_amdgcn_mfma_f32_16x16x32_bf16(aq[1], bk[sub][1], acc, 0, 0, 0);
            const int colg = (kb << 6) + sub * 16 + l15;
            #pragma unroll
            for (int r = 0; r < 4; ++r) {
                float e = padr[r] ? 1.0f
                        : ((colg <= rowg[r]) ? __builtin_amdgcn_exp2f(acc[r] * SCL2) : 0.0f);
                lsum[r] += e;
            }
        }
    }
    #pragma unroll
    for (int r = 0; r < 4; ++r) {    // reduce over the 16 lanes sharing this row group
        float v = lsum[r];
        v += __shfl_xor(v, 1); v += __shfl_xor(v, 2);
        v += __shfl_xor(v, 4); v += __shfl_xor(v, 8);
        lsum[r] = 1.0f / v;          // lsum becomes inv_l
    }

    // ================= pass 2: write p, accumulate O = P·V =================
    f32x4 oacc[4];
    #pragma unroll
    for (int i = 0; i < 4; ++i) oacc[i] = (f32x4){0.f, 0.f, 0.f, 0.f};

    for (int kb = 0; kb < kbCount; ++kb) {
        const short* kp = kb_base + (kb << 12);
        bf16x8 bk[4][2];
        #pragma unroll
        for (int sub = 0; sub < 4; ++sub) {
            bk[sub][0] = *(const bf16x8*)(kp + ((sub * 16 + l15) << 6));
            bk[sub][1] = *(const bf16x8*)(kp + ((sub * 16 + l15) << 6) + 32);
        }
        f32x4 s4[4];
        #pragma unroll
        for (int sub = 0; sub < 4; ++sub) {
            f32x4 acc = {0.f, 0.f, 0.f, 0.f};
            acc = __builtin_amdgcn_mfma_f32_16x16x32_bf16(aq[0], bk[sub][0], acc, 0, 0, 0);
            acc = __builtin_amdgcn_mfma_f32_16x16x32_bf16(aq[1], bk[sub][1], acc, 0, 0, 0);
            s4[sub] = acc;
        }

        // V fragments: issue now so the ~L2 latency hides under the exp/store phase
        const short* vp = vt_base + (kb << 6);
        bf16x8 bv[4][2];
        #pragma unroll
        for (int dsub = 0; dsub < 4; ++dsub) {
            bv[dsub][0] = *(const bf16x8*)(vp + (((size_t)(dsub * 16 + l15)) << 12));
            bv[dsub][1] = *(const bf16x8*)(vp + (((size_t)(dsub * 16 + l15)) << 12) + 32);
        }

        #pragma unroll
        for (int sub = 0; sub < 4; ++sub) {
            const int col  = sub * 16 + l15;
            const int colg = (kb << 6) + col;
            #pragma unroll
            for (int r = 0; r < 4; ++r) {
                float e = padr[r] ? 1.0f
                        : ((colg <= rowg[r]) ? __builtin_amdgcn_exp2f(s4[sub][r] * SCL2) : 0.0f);
                float p = e * lsum[r];
                attnRow[r][colg] = p;
                sP[wave][(quad * 4 + r) * PST + col] = f2bf(p);
            }
        }

        // sP round-trip (C layout -> A layout) — wave-private, no barrier needed
        #pragma unroll
        for (int ks = 0; ks < 2; ++ks) {
            bf16x8 ap = *(bf16x8*)&sP[wave][l15 * PST + ks * 32 + (quad << 3)];
            #pragma unroll
            for (int dsub = 0; dsub < 4; ++dsub)
                oacc[dsub] = __builtin_amdgcn_mfma_f32_16x16x32_bf16(ap, bv[dsub][ks], oacc[dsub], 0, 0, 0);
        }
    }

    // O already normalized (p used inv_l)
    #pragma unroll
    for (int dsub = 0; dsub < 4; ++dsub) {
        #pragma unroll
        for (int r = 0; r < 4; ++r) {
            Out[(((size_t)(b * LL + rowg[r])) << 6) + dsub * 16 + l15] = oacc[dsub][r];
        }
    }
}

extern "C" void kernel_launch(void* const* d_in, const int* in_sizes, int n_in,
                              void* d_out, int out_size, void* d_ws, size_t ws_size,
                              hipStream_t stream) {
    const float* Q = (const float*)d_in[0];
    const float* K = (const float*)d_in[1];
    const float* V = (const float*)d_in[2];
    const unsigned char* M = (const unsigned char*)d_in[3];
    float* Out  = (float*)d_out;                             // [B,L,D]
    float* Attn = (float*)d_out + (size_t)BB * LL * DD;      // [B,L,L]

    // workspace: Kb (8 MB bf16) + Vt (8 MB bf16 transposed)
    short* Kbf = (short*)d_ws;
    short* Vtr = Kbf + (size_t)BB * LL * DD;

    dim3 grid(LL / 64, BB);
    prep_kv<<<grid, 256, 0, stream>>>(K, V, Kbf, Vtr);
    attn_fused<<<grid, 256, 0, stream>>>(Q, Kbf, Vtr, M, Out, Attn);
}